// Round 1
// baseline (760.020 us; speedup 1.0000x reference)
//
#include <hip/hip_runtime.h>

// Fused recurrent linear attention (causal, unnormalized), fp32.
//   H_t = H_{t-1} + k_t v_t^T ;  o_t = (scale * q_t) @ H_t
// B=4, S=2048, H=16, D=128.
//
// Round 1 design: recurrent, register-resident state.
//  - grid = B*H*VSPLIT = 256 blocks (1 per CU). block = 256 threads.
//  - block handles (b,h) and a 32-column v-chunk; thread (vl,kg) owns
//    H[kg*16 .. kg*16+15][vc0+vl] in 16 VGPRs.
//  - time-tiled: TT=32 steps of k,q,v staged in LDS (40 KB), prefetched
//    into registers one tile ahead (2-barrier pattern) to hide HBM latency.
//  - dot over k reduced across 8 kg-threads with 3 in-wave shuffles
//    (kg = lane bits 0..2).
//  - o accumulated in LDS obuf, flushed coalesced (float4) per tile.

#define B_ 4
#define S_ 2048
#define H_ 16
#define D_ 128
#define VSPLIT 4
#define VC 32          // v-columns per block
#define KS 16          // k-rows per thread
#define TT 32          // time tile
#define NT (S_ / TT)   // 64 tiles
#define NTHREADS 256

__global__ __launch_bounds__(NTHREADS, 2)
void lin_attn_recurrent(const float* __restrict__ q,
                        const float* __restrict__ k,
                        const float* __restrict__ v,
                        float* __restrict__ o) {
  __shared__ float kbuf[TT * D_];   // 16 KB
  __shared__ float qbuf[TT * D_];   // 16 KB (pre-scaled)
  __shared__ float vbuf[TT * VC];   // 4 KB
  __shared__ float obuf[TT * VC];   // 4 KB

  const int tid = threadIdx.x;
  const int vl  = tid >> 3;   // 0..31 : local v column
  const int kg  = tid & 7;    // 0..7  : k group (lane bits 0..2)
  const int bh     = blockIdx.x >> 2;  // 0..63
  const int vchunk = blockIdx.x & 3;
  const int b = bh >> 4, h = bh & 15;
  const size_t base = (size_t)b * S_ * H_ * D_ + (size_t)h * D_;
  const int vc0 = vchunk * VC;
  const float scale = 0.08838834764831845f;  // 128^-0.5

  // Prefetch registers for one tile:
  //   k/q: 4 float4 per thread; f = n*256+tid -> tt=f>>5, d4=f&31
  //   v  : 1 float4 per thread; f = tid       -> tt=f>>3, d4=f&7
  float4 rk[4], rq[4], rv;

  auto prefetch = [&](int tile) {
    const size_t t0 = (size_t)tile * TT;
#pragma unroll
    for (int n = 0; n < 4; ++n) {
      const int f = n * NTHREADS + tid;
      const int tt = f >> 5, d4 = f & 31;
      const size_t g = base + (t0 + tt) * (size_t)(H_ * D_) + (size_t)d4 * 4;
      rk[n] = *(const float4*)(k + g);
      rq[n] = *(const float4*)(q + g);
    }
    {
      const int f = tid;
      const int tt = f >> 3, d4 = f & 7;
      const size_t g = base + (t0 + tt) * (size_t)(H_ * D_) + vc0 + (size_t)d4 * 4;
      rv = *(const float4*)(v + g);
    }
  };

  float st[KS];
#pragma unroll
  for (int j = 0; j < KS; ++j) st[j] = 0.f;

  prefetch(0);

  for (int tile = 0; tile < NT; ++tile) {
    __syncthreads();  // prev tile: LDS consumers + obuf flush done
    // stage regs -> LDS (word index == f*4, proven: (f>>5)*128+(f&31)*4 == f*4)
#pragma unroll
    for (int n = 0; n < 4; ++n) {
      const int f = n * NTHREADS + tid;
      *(float4*)(kbuf + (size_t)f * 4) = rk[n];
      float4 qs = rq[n];
      qs.x *= scale; qs.y *= scale; qs.z *= scale; qs.w *= scale;
      *(float4*)(qbuf + (size_t)f * 4) = qs;
    }
    *(float4*)(vbuf + (size_t)tid * 4) = rv;
    if (tile + 1 < NT) prefetch(tile + 1);  // hides HBM latency under compute
    __syncthreads();  // staging visible

    for (int tt = 0; tt < TT; ++tt) {
      const float vv = vbuf[tt * VC + vl];
      const float* kr = kbuf + tt * D_ + kg * KS;
      const float* qr = qbuf + tt * D_ + kg * KS;
      float acc = 0.f;
#pragma unroll
      for (int j = 0; j < KS; ++j) st[j] = fmaf(kr[j], vv, st[j]);
#pragma unroll
      for (int j = 0; j < KS; ++j) acc = fmaf(qr[j], st[j], acc);
      acc += __shfl_xor(acc, 1);
      acc += __shfl_xor(acc, 2);
      acc += __shfl_xor(acc, 4);
      if (kg == 0) obuf[tt * VC + vl] = acc;
    }
    __syncthreads();  // obuf complete; kbuf/qbuf reads done

    // flush obuf -> global, coalesced float4
    {
      const int f = tid;
      const int tt = f >> 3, d4 = f & 7;
      const size_t g = base + ((size_t)tile * TT + tt) * (size_t)(H_ * D_) + vc0 + (size_t)d4 * 4;
      *(float4*)(o + g) = *(const float4*)(obuf + (size_t)f * 4);
    }
  }
}

extern "C" void kernel_launch(void* const* d_in, const int* in_sizes, int n_in,
                              void* d_out, int out_size, void* d_ws, size_t ws_size,
                              hipStream_t stream) {
  const float* q = (const float*)d_in[0];
  const float* k = (const float*)d_in[1];
  const float* v = (const float*)d_in[2];
  float* o = (float*)d_out;
  dim3 grid(B_ * H_ * VSPLIT);   // 256 blocks
  dim3 block(NTHREADS);
  hipLaunchKernelGGL(lin_attn_recurrent, grid, block, 0, stream, q, k, v, o);
}

// Round 2
// 289.010 us; speedup vs baseline: 2.6297x; 2.6297x over previous
//
#include <hip/hip_runtime.h>

// Chunked linear attention (causal, unnormalized), bf16 MFMA, fp32 I/O.
//   Per (b,h), chunks of C=128:
//     S_n = K_n^T V_n                       (ph1, MFMA)
//     H_n = sum_{m<n} S_m  (excl. prefix)   (ph2, in-place in ws, fp32 acc)
//     O_n = tril(Qs K_n^T) V_n              (ph3a, MFMA, P via LDS)
//         + Qs H_n                          (ph3b, MFMA, RMW on o)
// B=4 S=2048 H=16 D=128 -> 64 bh chains, 16 chunks, 1024 parallel tiles.
// ws: 64*16*128*128 bf16 = 32 MiB (S_n then overwritten by H_n in-place).

#define Bc 4
#define Sq 2048
#define Hh 16
#define Dd 128
#define RS (Hh * Dd)      // 2048: stride between consecutive t
#define Cc 128
#define NCH (Sq / Cc)     // 16
#define BHt (Bc * Hh)     // 64

using frag_ab = __attribute__((ext_vector_type(8))) short;  // 8 bf16
using frag_cd = __attribute__((ext_vector_type(4))) float;  // 4 fp32

__device__ __forceinline__ unsigned short f2bf(float f) {
  union { float f; unsigned u; } x; x.f = f;
  unsigned r = x.u + 0x7FFFu + ((x.u >> 16) & 1u);  // RNE
  return (unsigned short)(r >> 16);
}
__device__ __forceinline__ float bf2f(unsigned short h) {
  union { unsigned u; float f; } x; x.u = ((unsigned)h) << 16; return x.f;
}
// XOR-swizzled element offsets (8-element granularity keeps b128 frag reads
// contiguous; XOR with row spreads banks -> ~conflict-free).
__device__ __forceinline__ int sw64(int r, int c) {
  return r * 64 + ((((c >> 3) ^ (r & 7)) << 3) | (c & 7));
}
__device__ __forceinline__ int sw128(int r, int c) {
  return r * 128 + ((((c >> 3) ^ (r & 15)) << 3) | (c & 7));
}

#define SCALE 0.08838834764831845f

// ---------------- Phase 1: S_n = K^T V (per bh, chunk) ----------------
__global__ __launch_bounds__(256) void ph1_ktv(const float* __restrict__ kg,
                                               const float* __restrict__ vg,
                                               unsigned short* __restrict__ st) {
  __shared__ unsigned short KT[128 * 64];  // [dk][t-half], swizzled, 16 KB
  __shared__ unsigned short VT[128 * 64];  // [dv][t-half]
  const int tid = threadIdx.x;
  const int bid = blockIdx.x;
  const int bh = bid >> 4, n = bid & 15;
  const int b = bh >> 4, h = bh & 15;
  const size_t cbase = (size_t)b * Sq * RS + (size_t)n * Cc * RS + (size_t)h * Dd;
  const int w = tid >> 6, L = tid & 63;
  const int wr = w >> 1, wc = w & 1, li = L & 15, q4 = L >> 4;

  frag_cd acc[4][4];
#pragma unroll
  for (int i = 0; i < 4; ++i)
#pragma unroll
    for (int j = 0; j < 4; ++j) acc[i][j] = (frag_cd){0.f, 0.f, 0.f, 0.f};

  for (int half = 0; half < 2; ++half) {
    __syncthreads();  // prev-half frag reads done before overwrite
    // stage K,V rows t in [64*half, 64*half+64), transposed to [d][t]
#pragma unroll
    for (int it = 0; it < 8; ++it) {
      const int sl = (tid & 15) | ((it & 3) << 4);          // 0..63
      const int c0 = ((tid >> 4) | ((it >> 2) << 4)) << 2;  // 0..124
      const int t = 64 * half + sl;
      const float4 k4 = *(const float4*)(kg + cbase + (size_t)t * RS + c0);
      const float4 v4 = *(const float4*)(vg + cbase + (size_t)t * RS + c0);
      KT[sw64(c0 + 0, sl)] = f2bf(k4.x);
      KT[sw64(c0 + 1, sl)] = f2bf(k4.y);
      KT[sw64(c0 + 2, sl)] = f2bf(k4.z);
      KT[sw64(c0 + 3, sl)] = f2bf(k4.w);
      VT[sw64(c0 + 0, sl)] = f2bf(v4.x);
      VT[sw64(c0 + 1, sl)] = f2bf(v4.y);
      VT[sw64(c0 + 2, sl)] = f2bf(v4.z);
      VT[sw64(c0 + 3, sl)] = f2bf(v4.w);
    }
    __syncthreads();
    // D[dv][dk] += A(=V^T)[dv][t] * B(=K)[t][dk]
#pragma unroll
    for (int kt = 0; kt < 2; ++kt) {
      frag_ab af[4], bf_[4];
#pragma unroll
      for (int mt = 0; mt < 4; ++mt)
        af[mt] = *(const frag_ab*)&VT[sw64(64 * wr + 16 * mt + li, 32 * kt + 8 * q4)];
#pragma unroll
      for (int nt = 0; nt < 4; ++nt)
        bf_[nt] = *(const frag_ab*)&KT[sw64(64 * wc + 16 * nt + li, 32 * kt + 8 * q4)];
#pragma unroll
      for (int mt = 0; mt < 4; ++mt)
#pragma unroll
        for (int nt = 0; nt < 4; ++nt)
          acc[mt][nt] = __builtin_amdgcn_mfma_f32_16x16x32_bf16(af[mt], bf_[nt], acc[mt][nt], 0, 0, 0);
    }
  }
  // store S_n bf16 at st[((bh*16+n)*128 + dv)*128 + dk]
  const size_t sb = (size_t)(bh * 16 + n) * (128 * 128);
#pragma unroll
  for (int mt = 0; mt < 4; ++mt)
#pragma unroll
    for (int nt = 0; nt < 4; ++nt)
#pragma unroll
      for (int r = 0; r < 4; ++r) {
        const int dv = 64 * wr + 16 * mt + 4 * q4 + r;
        const int dk = 64 * wc + 16 * nt + li;
        st[sb + (size_t)dv * 128 + dk] = f2bf(acc[mt][nt][r]);
      }
}

// ---------------- Phase 2: exclusive prefix over chunks (in-place) -----
__global__ __launch_bounds__(256) void ph2_prefix(unsigned short* __restrict__ st) {
  const int bid = blockIdx.x;        // BHt*8 = 512
  const int bh = bid >> 3, sl = bid & 7;
  const size_t base = (size_t)bh * NCH * (128 * 128) + (size_t)sl * 2048 +
                      (size_t)threadIdx.x * 8;
  float acc[8];
#pragma unroll
  for (int i = 0; i < 8; ++i) acc[i] = 0.f;
  for (int n = 0; n < NCH; ++n) {
    const size_t idx = base + (size_t)n * (128 * 128);
    const ushort4 s0 = *(const ushort4*)(st + idx);
    const ushort4 s1 = *(const ushort4*)(st + idx + 4);
    ushort4 h0, h1;
    h0.x = f2bf(acc[0]); h0.y = f2bf(acc[1]); h0.z = f2bf(acc[2]); h0.w = f2bf(acc[3]);
    h1.x = f2bf(acc[4]); h1.y = f2bf(acc[5]); h1.z = f2bf(acc[6]); h1.w = f2bf(acc[7]);
    *(ushort4*)(st + idx) = h0;
    *(ushort4*)(st + idx + 4) = h1;
    acc[0] += bf2f(s0.x); acc[1] += bf2f(s0.y); acc[2] += bf2f(s0.z); acc[3] += bf2f(s0.w);
    acc[4] += bf2f(s1.x); acc[5] += bf2f(s1.y); acc[6] += bf2f(s1.z); acc[7] += bf2f(s1.w);
  }
}

// ---------------- Phase 3a: O = tril(Qs K^T) V  (intra-chunk) ----------
__global__ __launch_bounds__(256) void ph3a_intra(const float* __restrict__ qg,
                                                  const float* __restrict__ kg,
                                                  const float* __restrict__ vg,
                                                  float* __restrict__ o) {
  __shared__ unsigned short A_[128 * 64];   // Q dk-half, later V^T s-half (16 KB)
  __shared__ unsigned short B_[128 * 64];   // K dk-half (16 KB)
  __shared__ unsigned short P_[128 * 128];  // P bf16 (32 KB)
  const int tid = threadIdx.x;
  const int bid = blockIdx.x;
  const int bh = bid >> 4, n = bid & 15;
  const int b = bh >> 4, h = bh & 15;
  const size_t cbase = (size_t)b * Sq * RS + (size_t)n * Cc * RS + (size_t)h * Dd;
  const int w = tid >> 6, L = tid & 63;
  const int wr = w >> 1, wc = w & 1, li = L & 15, q4 = L >> 4;

  frag_cd acc[4][4];
#pragma unroll
  for (int i = 0; i < 4; ++i)
#pragma unroll
    for (int j = 0; j < 4; ++j) acc[i][j] = (frag_cd){0.f, 0.f, 0.f, 0.f};

  // ---- GEMM1: P = Qs K^T (contract dk, staged in halves) ----
  for (int half = 0; half < 2; ++half) {
    __syncthreads();
#pragma unroll
    for (int it = 0; it < 8; ++it) {
      const int f = it * 256 + tid;      // 0..2047
      const int t = f >> 4;              // 0..127
      const int c0 = (f & 15) << 2;      // 0..60
      const float4 q4v = *(const float4*)(qg + cbase + (size_t)t * RS + 64 * half + c0);
      const float4 k4v = *(const float4*)(kg + cbase + (size_t)t * RS + 64 * half + c0);
      ushort4 qu, ku;
      qu.x = f2bf(q4v.x * SCALE); qu.y = f2bf(q4v.y * SCALE);
      qu.z = f2bf(q4v.z * SCALE); qu.w = f2bf(q4v.w * SCALE);
      ku.x = f2bf(k4v.x); ku.y = f2bf(k4v.y); ku.z = f2bf(k4v.z); ku.w = f2bf(k4v.w);
      *(ushort4*)&A_[sw64(t, c0)] = qu;
      *(ushort4*)&B_[sw64(t, c0)] = ku;
    }
    __syncthreads();
    if (64 * wc <= 64 * wr + 63) {  // wave (0,1) fully above diagonal: skip
#pragma unroll
      for (int kt = 0; kt < 2; ++kt) {
        frag_ab af[4], bf_[4];
#pragma unroll
        for (int mt = 0; mt < 4; ++mt)
          af[mt] = *(const frag_ab*)&A_[sw64(64 * wr + 16 * mt + li, 32 * kt + 8 * q4)];
#pragma unroll
        for (int nt = 0; nt < 4; ++nt)
          bf_[nt] = *(const frag_ab*)&B_[sw64(64 * wc + 16 * nt + li, 32 * kt + 8 * q4)];
#pragma unroll
        for (int mt = 0; mt < 4; ++mt)
#pragma unroll
          for (int nt = 0; nt < 4; ++nt)
            if (64 * wc + 16 * nt <= 64 * wr + 16 * mt + 15)
              acc[mt][nt] = __builtin_amdgcn_mfma_f32_16x16x32_bf16(af[mt], bf_[nt], acc[mt][nt], 0, 0, 0);
      }
    }
  }
  // ---- mask (s<=t incl. diagonal) and write P to LDS (C/D layout known) ----
#pragma unroll
  for (int mt = 0; mt < 4; ++mt)
#pragma unroll
    for (int nt = 0; nt < 4; ++nt) {
      const int t0 = 64 * wr + 16 * mt + 4 * q4;
      const int s = 64 * wc + 16 * nt + li;
#pragma unroll
      for (int r = 0; r < 4; ++r) {
        const int t = t0 + r;
        P_[sw128(t, s)] = (s <= t) ? f2bf(acc[mt][nt][r]) : (unsigned short)0;
      }
    }
#pragma unroll
  for (int i = 0; i < 4; ++i)
#pragma unroll
    for (int j = 0; j < 4; ++j) acc[i][j] = (frag_cd){0.f, 0.f, 0.f, 0.f};

  // ---- GEMM2: O = P V (contract s; V^T staged into A_ in halves) ----
  for (int half = 0; half < 2; ++half) {
    __syncthreads();  // P_ visible; A_ (Q) reads done
#pragma unroll
    for (int it = 0; it < 8; ++it) {
      const int sl = (tid & 15) | ((it & 3) << 4);
      const int c0 = ((tid >> 4) | ((it >> 2) << 4)) << 2;
      const int s = 64 * half + sl;
      const float4 v4v = *(const float4*)(vg + cbase + (size_t)s * RS + c0);
      A_[sw64(c0 + 0, sl)] = f2bf(v4v.x);
      A_[sw64(c0 + 1, sl)] = f2bf(v4v.y);
      A_[sw64(c0 + 2, sl)] = f2bf(v4v.z);
      A_[sw64(c0 + 3, sl)] = f2bf(v4v.w);
    }
    __syncthreads();
#pragma unroll
    for (int kt = 0; kt < 2; ++kt) {
      const int ktg = 2 * half + kt;              // global s-tile 0..3
      if (32 * ktg > 64 * wr + 63) continue;      // whole s-tile above diag
      frag_ab af[4], bf_[4];
#pragma unroll
      for (int mt = 0; mt < 4; ++mt)
        af[mt] = *(const frag_ab*)&P_[sw128(64 * wr + 16 * mt + li, 32 * ktg + 8 * q4)];
#pragma unroll
      for (int nt = 0; nt < 4; ++nt)
        bf_[nt] = *(const frag_ab*)&A_[sw64(64 * wc + 16 * nt + li, 32 * kt + 8 * q4)];
#pragma unroll
      for (int mt = 0; mt < 4; ++mt)
#pragma unroll
        for (int nt = 0; nt < 4; ++nt)
          if (32 * ktg <= 64 * wr + 16 * mt + 15)
            acc[mt][nt] = __builtin_amdgcn_mfma_f32_16x16x32_bf16(af[mt], bf_[nt], acc[mt][nt], 0, 0, 0);
    }
  }
  // store O (intra part), fp32
#pragma unroll
  for (int mt = 0; mt < 4; ++mt)
#pragma unroll
    for (int nt = 0; nt < 4; ++nt)
#pragma unroll
      for (int r = 0; r < 4; ++r) {
        const int t = 64 * wr + 16 * mt + 4 * q4 + r;
        const int dv = 64 * wc + 16 * nt + li;
        o[cbase + (size_t)t * RS + dv] = acc[mt][nt][r];
      }
}

// ---------------- Phase 3b: O += Qs H_n  (inter-chunk) -----------------
__global__ __launch_bounds__(256) void ph3b_inter(const float* __restrict__ qg,
                                                  const unsigned short* __restrict__ st,
                                                  float* __restrict__ o) {
  __shared__ unsigned short Qf[128 * 128];  // Qs full, 32 KB
  __shared__ unsigned short Hb[128 * 64];   // H^T[dv][dk-half], 16 KB
  const int tid = threadIdx.x;
  const int bid = blockIdx.x;
  const int bh = bid >> 4, n = bid & 15;
  const int b = bh >> 4, h = bh & 15;
  const size_t cbase = (size_t)b * Sq * RS + (size_t)n * Cc * RS + (size_t)h * Dd;
  const size_t sb = (size_t)(bh * 16 + n) * (128 * 128);
  const int w = tid >> 6, L = tid & 63;
  const int wr = w >> 1, wc = w & 1, li = L & 15, q4 = L >> 4;

  // stage Qs full (scaled)
#pragma unroll
  for (int it = 0; it < 16; ++it) {
    const int f = it * 256 + tid;      // 0..4095
    const int t = f >> 5;              // 0..127
    const int c0 = (f & 31) << 2;      // 0..124
    const float4 q4v = *(const float4*)(qg + cbase + (size_t)t * RS + c0);
    ushort4 qu;
    qu.x = f2bf(q4v.x * SCALE); qu.y = f2bf(q4v.y * SCALE);
    qu.z = f2bf(q4v.z * SCALE); qu.w = f2bf(q4v.w * SCALE);
    *(ushort4*)&Qf[sw128(t, c0)] = qu;
  }
  frag_cd acc[4][4];
#pragma unroll
  for (int i = 0; i < 4; ++i)
#pragma unroll
    for (int j = 0; j < 4; ++j) acc[i][j] = (frag_cd){0.f, 0.f, 0.f, 0.f};

  for (int half = 0; half < 2; ++half) {
    __syncthreads();  // half0: Qf visible; half1: Hb reads done
    // stage H^T dk-half (already bf16 in ws): 16B copies
#pragma unroll
    for (int it = 0; it < 4; ++it) {
      const int f = it * 256 + tid;    // 0..1023
      const int dv = f >> 3;           // 0..127
      const int c8 = (f & 7) << 3;     // 0..56
      const uint4 hv = *(const uint4*)(st + sb + (size_t)dv * 128 + 64 * half + c8);
      *(uint4*)&Hb[sw64(dv, c8)] = hv;
    }
    __syncthreads();
#pragma unroll
    for (int kt = 0; kt < 2; ++kt) {
      const int ktg = 2 * half + kt;
      frag_ab af[4], bf_[4];
#pragma unroll
      for (int mt = 0; mt < 4; ++mt)
        af[mt] = *(const frag_ab*)&Qf[sw128(64 * wr + 16 * mt + li, 32 * ktg + 8 * q4)];
#pragma unroll
      for (int nt = 0; nt < 4; ++nt)
        bf_[nt] = *(const frag_ab*)&Hb[sw64(64 * wc + 16 * nt + li, 32 * kt + 8 * q4)];
#pragma unroll
      for (int mt = 0; mt < 4; ++mt)
#pragma unroll
        for (int nt = 0; nt < 4; ++nt)
          acc[mt][nt] = __builtin_amdgcn_mfma_f32_16x16x32_bf16(af[mt], bf_[nt], acc[mt][nt], 0, 0, 0);
    }
  }
  // O += (read-modify-write; ph3a ran earlier on same stream)
#pragma unroll
  for (int mt = 0; mt < 4; ++mt)
#pragma unroll
    for (int nt = 0; nt < 4; ++nt)
#pragma unroll
      for (int r = 0; r < 4; ++r) {
        const int t = 64 * wr + 16 * mt + 4 * q4 + r;
        const int dv = 64 * wc + 16 * nt + li;
        const size_t oi = cbase + (size_t)t * RS + dv;
        o[oi] += acc[mt][nt][r];
      }
}

extern "C" void kernel_launch(void* const* d_in, const int* in_sizes, int n_in,
                              void* d_out, int out_size, void* d_ws, size_t ws_size,
                              hipStream_t stream) {
  const float* q = (const float*)d_in[0];
  const float* k = (const float*)d_in[1];
  const float* v = (const float*)d_in[2];
  float* o = (float*)d_out;
  unsigned short* st = (unsigned short*)d_ws;  // needs 32 MiB
  hipLaunchKernelGGL(ph1_ktv, dim3(BHt * NCH), dim3(256), 0, stream, k, v, st);
  hipLaunchKernelGGL(ph2_prefix, dim3(BHt * 8), dim3(256), 0, stream, st);
  hipLaunchKernelGGL(ph3a_intra, dim3(BHt * NCH), dim3(256), 0, stream, q, k, v, o);
  hipLaunchKernelGGL(ph3b_inter, dim3(BHt * NCH), dim3(256), 0, stream, q, st, o);
}

// Round 3
// 274.898 us; speedup vs baseline: 2.7647x; 1.0513x over previous
//
#include <hip/hip_runtime.h>

// Chunked linear attention (causal, unnormalized), bf16 MFMA, fp32 I/O.
// R3: two fused kernels.
//   phA: per (bh, dv-slice16), loop chunks n=0..15:
//        store H_n (exclusive prefix, bf16 -> ws), acc += K_n^T V_n via MFMA
//        (never-zeroed accumulators ARE the prefix sum; ph2 eliminated)
//   phB: per (bh, n): O = Qs*H_n + tril(Qs*K_n^T)*V_n  (single O write)
// B=4 S=2048 H=16 D=128. ws: 64*16*128*128 bf16 = 32 MiB.

#define Bc 4
#define Sq 2048
#define Hh 16
#define Dd 128
#define RS (Hh * Dd)      // 2048
#define Cc 128
#define NCH (Sq / Cc)     // 16
#define BHt (Bc * Hh)     // 64
#define SCALE 0.08838834764831845f

using frag_ab = __attribute__((ext_vector_type(8))) short;  // 8 bf16
using frag_cd = __attribute__((ext_vector_type(4))) float;  // 4 fp32

__device__ __forceinline__ unsigned short f2bf(float f) {
  union { float f; unsigned u; } x; x.f = f;
  unsigned r = x.u + 0x7FFFu + ((x.u >> 16) & 1u);  // RNE
  return (unsigned short)(r >> 16);
}
// swizzles: permute 8-element (16 B) blocks within a row -> frag b128 reads
// stay contiguous; writes spread across banks.
__device__ __forceinline__ int sw64(int r, int c) {
  return r * 64 + ((((c >> 3) ^ (r & 7)) << 3) | (c & 7));
}
__device__ __forceinline__ int sw128(int r, int c) {
  return r * 128 + ((((c >> 3) ^ (r & 15)) << 3) | (c & 7));
}
__device__ __forceinline__ int swKT(int dk, int t) {  // [dk 128][t 128]
  return dk * 128 + ((((t >> 3) ^ (dk ^ (dk >> 4))) & 15) << 3) + (t & 7);
}
__device__ __forceinline__ int swVT(int dv, int t) {  // [dv 16][t 128]
  return dv * 128 + ((((t >> 3) ^ dv) & 15) << 3) + (t & 7);
}

// ---------- phA: running state, H_n = sum_{m<n} K_m^T V_m ----------
// grid 512: bh = bid & 63 (XCD-colocates the 8 dv-slices of one bh so L2
// absorbs the 8x redundant K read), slice = bid >> 6.
__global__ __launch_bounds__(256) void phA_state(const float* __restrict__ kg,
                                                 const float* __restrict__ vg,
                                                 unsigned short* __restrict__ st) {
  __shared__ unsigned short KT[128 * 128];  // 32 KB [dk][t]
  __shared__ unsigned short VT[16 * 128];   //  4 KB [dv][t]
  const int tid = threadIdx.x;
  const int bh = blockIdx.x & 63, slice = blockIdx.x >> 6;
  const int b = bh >> 4, h = bh & 15;
  const int dv0 = slice * 16;
  const size_t base = (size_t)b * Sq * RS + (size_t)h * Dd;
  const int w = tid >> 6, L = tid & 63, li = L & 15, q4 = L >> 4;
  // K staging: thread owns a 4t x 4dk micro-tile per pass (gather transpose)
  const int kdk0 = (tid & 31) * 4;
  const int ktg4 = (tid >> 5) * 4;      // t sub-offset 0..28
  // V staging: thread owns 2t x 4dv
  const int vdv0l = (tid & 3) * 4;
  const int vt0 = (tid >> 2) * 2;       // 0..126

  float4 rk[4][4];
  float4 rv[2];
  auto prefetch = [&](int n) {
    const size_t t0g = (size_t)n * Cc;
#pragma unroll
    for (int p = 0; p < 4; ++p) {
      const int t0 = p * 32 + ktg4;
#pragma unroll
      for (int i = 0; i < 4; ++i)
        rk[p][i] = *(const float4*)(kg + base + (t0g + t0 + i) * (size_t)RS + kdk0);
    }
#pragma unroll
    for (int i = 0; i < 2; ++i)
      rv[i] = *(const float4*)(vg + base + (t0g + vt0 + i) * (size_t)RS + dv0 + vdv0l);
  };

  frag_cd acc[2];
  acc[0] = (frag_cd){0.f, 0.f, 0.f, 0.f};
  acc[1] = (frag_cd){0.f, 0.f, 0.f, 0.f};
  prefetch(0);
  const size_t sbb = (size_t)bh * NCH * (128 * 128);

  for (int n = 0; n < NCH; ++n) {
    __syncthreads();  // prev chunk's frag reads done
    // stage K^T (ushort4 along t) and V^T (ushort2 along t)
#pragma unroll
    for (int p = 0; p < 4; ++p) {
      const int t0 = p * 32 + ktg4;
#pragma unroll
      for (int j = 0; j < 4; ++j) {
        ushort4 u;
        u.x = f2bf(((const float*)&rk[p][0])[j]);
        u.y = f2bf(((const float*)&rk[p][1])[j]);
        u.z = f2bf(((const float*)&rk[p][2])[j]);
        u.w = f2bf(((const float*)&rk[p][3])[j]);
        *(ushort4*)&KT[swKT(kdk0 + j, t0)] = u;
      }
    }
#pragma unroll
    for (int j = 0; j < 4; ++j) {
      ushort2 u;
      u.x = f2bf(((const float*)&rv[0])[j]);
      u.y = f2bf(((const float*)&rv[1])[j]);
      *(ushort2*)&VT[swVT(vdv0l + j, vt0)] = u;
    }
    if (n + 1 < NCH) prefetch(n + 1);  // HBM latency hides under LDS+MFMA
    __syncthreads();
    // store EXCLUSIVE state H_n (acc before this chunk's contribution)
    const size_t sb = sbb + (size_t)n * (128 * 128);
#pragma unroll
    for (int nt = 0; nt < 2; ++nt)
#pragma unroll
      for (int r = 0; r < 4; ++r) {
        const int dv = dv0 + 4 * q4 + r;
        const int dk = 32 * w + 16 * nt + li;
        st[sb + (size_t)dv * 128 + dk] = f2bf(acc[nt][r]);
      }
    // acc[dv][dk] += V^T K  (wave w owns dk in [32w, 32w+32))
#pragma unroll
    for (int kt = 0; kt < 4; ++kt) {
      frag_ab af = *(const frag_ab*)&VT[swVT(li, 32 * kt + 8 * q4)];
#pragma unroll
      for (int nt = 0; nt < 2; ++nt) {
        frag_ab bf = *(const frag_ab*)&KT[swKT(32 * w + 16 * nt + li, 32 * kt + 8 * q4)];
        acc[nt] = __builtin_amdgcn_mfma_f32_16x16x32_bf16(af, bf, acc[nt], 0, 0, 0);
      }
    }
  }
}

// ---------- phB: O = Qs*H_n + tril(Qs*K^T)*V ----------
__global__ __launch_bounds__(256) void phB_out(const float* __restrict__ qg,
                                               const float* __restrict__ kg,
                                               const float* __restrict__ vg,
                                               const unsigned short* __restrict__ st,
                                               float* __restrict__ o) {
  __shared__ unsigned short QP[128 * 128];  // 32 KB: Qs, later P
  __shared__ unsigned short Bb[128 * 64];   // 16 KB: H / K / V^T halves
  const int tid = threadIdx.x;
  const int bid = blockIdx.x;
  const int bh = bid >> 4, n = bid & 15;
  const int b = bh >> 4, h = bh & 15;
  const size_t cbase = (size_t)b * Sq * RS + (size_t)n * Cc * RS + (size_t)h * Dd;
  const size_t sb = (size_t)(bh * 16 + n) * (128 * 128);
  const int w = tid >> 6, L = tid & 63;
  const int wr = w >> 1, wc = w & 1, li = L & 15, q4 = L >> 4;

  // stage Qs full (scaled) -> QP
#pragma unroll
  for (int it = 0; it < 16; ++it) {
    const int f = it * 256 + tid;
    const int t = f >> 5;
    const int c0 = (f & 31) << 2;
    const float4 q4v = *(const float4*)(qg + cbase + (size_t)t * RS + c0);
    ushort4 qu;
    qu.x = f2bf(q4v.x * SCALE); qu.y = f2bf(q4v.y * SCALE);
    qu.z = f2bf(q4v.z * SCALE); qu.w = f2bf(q4v.w * SCALE);
    *(ushort4*)&QP[sw128(t, c0)] = qu;
  }
  frag_cd accO[4][4], accP[4][4];
#pragma unroll
  for (int i = 0; i < 4; ++i)
#pragma unroll
    for (int j = 0; j < 4; ++j) {
      accO[i][j] = (frag_cd){0.f, 0.f, 0.f, 0.f};
      accP[i][j] = (frag_cd){0.f, 0.f, 0.f, 0.f};
    }

  // ---- H-GEMM: accO = Qs (from QP) x H  (H in ws is [dv][dk]) ----
  for (int half = 0; half < 2; ++half) {
    __syncthreads();  // half0: QP visible; half1: Bb reads done
#pragma unroll
    for (int it = 0; it < 4; ++it) {
      const int f = it * 256 + tid;
      const int dv = f >> 3;
      const int c8 = (f & 7) << 3;
      const uint4 hv = *(const uint4*)(st + sb + (size_t)dv * 128 + 64 * half + c8);
      *(uint4*)&Bb[sw64(dv, c8)] = hv;
    }
    __syncthreads();
#pragma unroll
    for (int kt = 0; kt < 2; ++kt) {
      const int ktg = 2 * half + kt;
      frag_ab af[4], bf_[4];
#pragma unroll
      for (int mt = 0; mt < 4; ++mt)
        af[mt] = *(const frag_ab*)&QP[sw128(64 * wr + 16 * mt + li, 32 * ktg + 8 * q4)];
#pragma unroll
      for (int nt = 0; nt < 4; ++nt)
        bf_[nt] = *(const frag_ab*)&Bb[sw64(64 * wc + 16 * nt + li, 32 * kt + 8 * q4)];
#pragma unroll
      for (int mt = 0; mt < 4; ++mt)
#pragma unroll
        for (int nt = 0; nt < 4; ++nt)
          accO[mt][nt] = __builtin_amdgcn_mfma_f32_16x16x32_bf16(af[mt], bf_[nt], accO[mt][nt], 0, 0, 0);
    }
  }

  // ---- GEMM1: accP = Qs x K^T (triangle-skipped) ----
  for (int half = 0; half < 2; ++half) {
    __syncthreads();
#pragma unroll
    for (int it = 0; it < 8; ++it) {
      const int f = it * 256 + tid;
      const int t = f >> 4;
      const int c0 = (f & 15) << 2;
      const float4 k4v = *(const float4*)(kg + cbase + (size_t)t * RS + 64 * half + c0);
      ushort4 ku;
      ku.x = f2bf(k4v.x); ku.y = f2bf(k4v.y); ku.z = f2bf(k4v.z); ku.w = f2bf(k4v.w);
      *(ushort4*)&Bb[sw64(t, c0)] = ku;
    }
    __syncthreads();
    if (64 * wc <= 64 * wr + 63) {
#pragma unroll
      for (int kt = 0; kt < 2; ++kt) {
        const int ktg = 2 * half + kt;
        frag_ab af[4], bf_[4];
#pragma unroll
        for (int mt = 0; mt < 4; ++mt)
          af[mt] = *(const frag_ab*)&QP[sw128(64 * wr + 16 * mt + li, 32 * ktg + 8 * q4)];
#pragma unroll
        for (int nt = 0; nt < 4; ++nt)
          bf_[nt] = *(const frag_ab*)&Bb[sw64(64 * wc + 16 * nt + li, 32 * kt + 8 * q4)];
#pragma unroll
        for (int mt = 0; mt < 4; ++mt)
#pragma unroll
          for (int nt = 0; nt < 4; ++nt)
            if (64 * wc + 16 * nt <= 64 * wr + 16 * mt + 15)
              accP[mt][nt] = __builtin_amdgcn_mfma_f32_16x16x32_bf16(af[mt], bf_[nt], accP[mt][nt], 0, 0, 0);
      }
    }
  }
  __syncthreads();  // all QP (Qs) reads done -> safe to overwrite with P
  // masked P (s<=t) -> QP
#pragma unroll
  for (int mt = 0; mt < 4; ++mt)
#pragma unroll
    for (int nt = 0; nt < 4; ++nt) {
      const int t0 = 64 * wr + 16 * mt + 4 * q4;
      const int s = 64 * wc + 16 * nt + li;
#pragma unroll
      for (int r = 0; r < 4; ++r) {
        const int t = t0 + r;
        QP[sw128(t, s)] = (s <= t) ? f2bf(accP[mt][nt][r]) : (unsigned short)0;
      }
    }

  // ---- GEMM2: accO += P x V  (V^T staged into Bb) ----
  for (int half = 0; half < 2; ++half) {
    __syncthreads();  // P visible / Bb reads done
#pragma unroll
    for (int it = 0; it < 8; ++it) {
      const int sl = (tid & 15) | ((it & 3) << 4);
      const int c0 = ((tid >> 4) | ((it >> 2) << 4)) << 2;
      const int s = 64 * half + sl;
      const float4 v4v = *(const float4*)(vg + cbase + (size_t)s * RS + c0);
      Bb[sw64(c0 + 0, sl)] = f2bf(v4v.x);
      Bb[sw64(c0 + 1, sl)] = f2bf(v4v.y);
      Bb[sw64(c0 + 2, sl)] = f2bf(v4v.z);
      Bb[sw64(c0 + 3, sl)] = f2bf(v4v.w);
    }
    __syncthreads();
#pragma unroll
    for (int kt = 0; kt < 2; ++kt) {
      const int ktg = 2 * half + kt;
      if (32 * ktg > 64 * wr + 63) continue;
      frag_ab af[4], bf_[4];
#pragma unroll
      for (int mt = 0; mt < 4; ++mt)
        af[mt] = *(const frag_ab*)&QP[sw128(64 * wr + 16 * mt + li, 32 * ktg + 8 * q4)];
#pragma unroll
      for (int nt = 0; nt < 4; ++nt)
        bf_[nt] = *(const frag_ab*)&Bb[sw64(64 * wc + 16 * nt + li, 32 * kt + 8 * q4)];
#pragma unroll
      for (int mt = 0; mt < 4; ++mt)
#pragma unroll
        for (int nt = 0; nt < 4; ++nt)
          if (32 * ktg <= 64 * wr + 16 * mt + 15)
            accO[mt][nt] = __builtin_amdgcn_mfma_f32_16x16x32_bf16(af[mt], bf_[nt], accO[mt][nt], 0, 0, 0);
    }
  }
  // store O fp32 (single write, no RMW)
#pragma unroll
  for (int mt = 0; mt < 4; ++mt)
#pragma unroll
    for (int nt = 0; nt < 4; ++nt)
#pragma unroll
      for (int r = 0; r < 4; ++r) {
        const int t = 64 * wr + 16 * mt + 4 * q4 + r;
        const int dv = 64 * wc + 16 * nt + li;
        o[cbase + (size_t)t * RS + dv] = accO[mt][nt][r];
      }
}

extern "C" void kernel_launch(void* const* d_in, const int* in_sizes, int n_in,
                              void* d_out, int out_size, void* d_ws, size_t ws_size,
                              hipStream_t stream) {
  const float* q = (const float*)d_in[0];
  const float* k = (const float*)d_in[1];
  const float* v = (const float*)d_in[2];
  float* o = (float*)d_out;
  unsigned short* st = (unsigned short*)d_ws;  // 32 MiB
  hipLaunchKernelGGL(phA_state, dim3(BHt * 8), dim3(256), 0, stream, k, v, st);
  hipLaunchKernelGGL(phB_out, dim3(BHt * NCH), dim3(256), 0, stream, q, k, v, st, o);
}